// Round 1
// baseline (95.564 us; speedup 1.0000x reference)
//
#include <hip/hip_runtime.h>
#include <math.h>

// B=4, T=2048, C=768, H=64
#define TB 2048
#define CB 768
#define HB 64
#define NB 4

typedef __attribute__((ext_vector_type(8))) short bf16x8;
typedef __attribute__((ext_vector_type(4))) float f32x4;

__device__ inline unsigned short f2bf(float f) {
  union { float f; unsigned u; } v; v.f = f;
  unsigned r = v.u + 0x7FFFu + ((v.u >> 16) & 1u);
  return (unsigned short)(r >> 16);
}

// ---------------- kernel 0: weights fp32 [C][64] x3 -> Wt bf16 [192][768] ----
__global__ void cvt_w_kernel(const float* __restrict__ Wq, const float* __restrict__ Wk,
                             const float* __restrict__ Wv, unsigned short* __restrict__ Wt) {
  int id = blockIdx.x * 256 + threadIdx.x;
  if (id >= 192 * CB) return;
  int j = id / CB, c = id - j * CB;
  const float* W = (j < 64) ? Wq : (j < 128) ? Wk : Wv;
  Wt[id] = f2bf(W[c * 64 + (j & 63)]);
}

// ---------------- kernel 1: QKV projection GEMM ------------------------------
// x [8192][768] fp32  @  Wt^T -> q,k [8192][64] bf16, vT [4][64][2048] bf16
__launch_bounds__(256)
__global__ void proj_kernel(const float* __restrict__ x, const unsigned short* __restrict__ Wt,
                            unsigned short* __restrict__ qo, unsigned short* __restrict__ ko,
                            unsigned short* __restrict__ vT) {
  __shared__ __align__(16) unsigned short xs[64 * 64]; // 64 rows x 64 k, bf16, XOR-swizzled
  const int tid = threadIdx.x;
  const int wv = tid >> 6;
  const int l = tid & 63;
  const int lrow = l & 15, lg = l >> 4;
  const int m0 = blockIdx.x * 64;
  const int srow = tid >> 2;  // staging: row 0..63
  const int sq = tid & 3;     // staging: 16-col quarter
  const float* xp = x + (size_t)(m0 + srow) * CB + sq * 16;

  f32x4 acc[4][3];
#pragma unroll
  for (int a = 0; a < 4; ++a)
#pragma unroll
    for (int n = 0; n < 3; ++n) acc[a][n] = (f32x4){0.f, 0.f, 0.f, 0.f};

  for (int k0 = 0; k0 < CB; k0 += 64) {
    // stage 64x64 fp32 -> bf16 LDS (swizzled)
    bf16x8 c0, c1;
#pragma unroll
    for (int i = 0; i < 2; ++i) {
      float4 f = *(const float4*)(xp + k0 + 4 * i);
      c0[4 * i + 0] = (short)f2bf(f.x); c0[4 * i + 1] = (short)f2bf(f.y);
      c0[4 * i + 2] = (short)f2bf(f.z); c0[4 * i + 3] = (short)f2bf(f.w);
    }
#pragma unroll
    for (int i = 0; i < 2; ++i) {
      float4 f = *(const float4*)(xp + k0 + 8 + 4 * i);
      c1[4 * i + 0] = (short)f2bf(f.x); c1[4 * i + 1] = (short)f2bf(f.y);
      c1[4 * i + 2] = (short)f2bf(f.z); c1[4 * i + 3] = (short)f2bf(f.w);
    }
    {
      char* base = (char*)xs + srow * 128;
      int swz = (srow & 7) << 4;
      *(bf16x8*)(base + ((sq * 32 + 0) ^ swz)) = c0;
      *(bf16x8*)(base + ((sq * 32 + 16) ^ swz)) = c1;
    }
    __syncthreads();

#pragma unroll
    for (int s = 0; s < 2; ++s) {
      bf16x8 af[4], bfr[3];
#pragma unroll
      for (int mf = 0; mf < 4; ++mf) {
        int r = mf * 16 + lrow;
        af[mf] = *(const bf16x8*)((const char*)xs + r * 128 +
                                  ((s * 64 + lg * 16) ^ ((r & 7) << 4)));
      }
#pragma unroll
      for (int nf = 0; nf < 3; ++nf) {
        int col = wv * 48 + nf * 16 + lrow;
        bfr[nf] = *(const bf16x8*)(Wt + (size_t)col * CB + k0 + s * 32 + lg * 8);
      }
#pragma unroll
      for (int mf = 0; mf < 4; ++mf)
#pragma unroll
        for (int nf = 0; nf < 3; ++nf)
          acc[mf][nf] = __builtin_amdgcn_mfma_f32_16x16x32_bf16(af[mf], bfr[nf], acc[mf][nf], 0, 0, 0);
    }
    __syncthreads();
  }

  // epilogue: D row = 16*mf + 4*lg + r, col = 48*wv + 16*nf + lrow
#pragma unroll
  for (int mf = 0; mf < 4; ++mf)
#pragma unroll
    for (int nf = 0; nf < 3; ++nf)
#pragma unroll
      for (int r = 0; r < 4; ++r) {
        int grow = m0 + mf * 16 + lg * 4 + r;
        int j = wv * 48 + nf * 16 + lrow;
        unsigned short val = f2bf(acc[mf][nf][r]);
        if (j < 64) {
          qo[(size_t)grow * 64 + j] = val;
        } else if (j < 128) {
          ko[(size_t)grow * 64 + (j - 64)] = val;
        } else {
          int bb = grow >> 11, t = grow & (TB - 1);
          vT[((size_t)bb * 64 + (j - 128)) * TB + t] = val;
        }
      }
}

// ---------------- kernel 2: causal flash attention ---------------------------
// grid (T/32, B), block 128 (2 waves x 16 Q-rows)
__launch_bounds__(128)
__global__ void attn_kernel(const unsigned short* __restrict__ q,
                            const unsigned short* __restrict__ k,
                            const unsigned short* __restrict__ vT,
                            float* __restrict__ out) {
  __shared__ __align__(16) unsigned short Pl[2][16][72]; // per-wave P tile, +8 pad
  const int tid = threadIdx.x;
  const int wv = tid >> 6, l = tid & 63;
  const int lrow = l & 15, lg = l >> 4;
  const int b = blockIdx.y;
  const int q0w = blockIdx.x * 32 + wv * 16;
  const unsigned short* qb = q + (size_t)b * TB * 64;
  const unsigned short* kb = k + (size_t)b * TB * 64;
  const unsigned short* vb = vT + (size_t)b * 64 * TB;

  bf16x8 qf[2];
#pragma unroll
  for (int s = 0; s < 2; ++s)
    qf[s] = *(const bf16x8*)(qb + (size_t)(q0w + lrow) * 64 + s * 32 + lg * 8);

  float m[4], ls[4];
  f32x4 o[4];
#pragma unroll
  for (int r = 0; r < 4; ++r) { m[r] = -INFINITY; ls[r] = 0.f; }
#pragma unroll
  for (int hf = 0; hf < 4; ++hf) o[hf] = (f32x4){0.f, 0.f, 0.f, 0.f};

  const int kvmax = q0w + 15;
  const float scale = 0.03608439182435161f; // 768^-0.5

  for (int kv0 = 0; kv0 <= kvmax; kv0 += 64) {
    f32x4 S[4];
#pragma unroll
    for (int cf = 0; cf < 4; ++cf) S[cf] = (f32x4){0.f, 0.f, 0.f, 0.f};
#pragma unroll
    for (int cf = 0; cf < 4; ++cf) {
      const unsigned short* kp = kb + (size_t)(kv0 + cf * 16 + lrow) * 64 + lg * 8;
#pragma unroll
      for (int s = 0; s < 2; ++s) {
        bf16x8 kf = *(const bf16x8*)(kp + s * 32);
        S[cf] = __builtin_amdgcn_mfma_f32_16x16x32_bf16(qf[s], kf, S[cf], 0, 0, 0);
      }
    }
    const bool msk = (kv0 + 63 > q0w);
#pragma unroll
    for (int cf = 0; cf < 4; ++cf)
#pragma unroll
      for (int r = 0; r < 4; ++r) {
        float vv = S[cf][r] * scale;
        if (msk) {
          int rw = q0w + lg * 4 + r, cl = kv0 + cf * 16 + lrow;
          if (cl > rw) vv = -INFINITY;
        }
        S[cf][r] = vv;
      }
    float fr[4], rs[4];
#pragma unroll
    for (int r = 0; r < 4; ++r) {
      float v = fmaxf(fmaxf(S[0][r], S[1][r]), fmaxf(S[2][r], S[3][r]));
      v = fmaxf(v, __shfl_xor(v, 1, 16));
      v = fmaxf(v, __shfl_xor(v, 2, 16));
      v = fmaxf(v, __shfl_xor(v, 4, 16));
      v = fmaxf(v, __shfl_xor(v, 8, 16));
      float mn = fmaxf(m[r], v);
      fr[r] = __expf(m[r] - mn);
      m[r] = mn;
      rs[r] = 0.f;
    }
#pragma unroll
    for (int cf = 0; cf < 4; ++cf)
#pragma unroll
      for (int r = 0; r < 4; ++r) {
        float p = __expf(S[cf][r] - m[r]); // masked: exp(-inf) = 0
        S[cf][r] = p;
        rs[r] += p;
      }
#pragma unroll
    for (int r = 0; r < 4; ++r) {
      float v = rs[r];
      v += __shfl_xor(v, 1, 16);
      v += __shfl_xor(v, 2, 16);
      v += __shfl_xor(v, 4, 16);
      v += __shfl_xor(v, 8, 16);
      ls[r] = ls[r] * fr[r] + v;
#pragma unroll
      for (int hf = 0; hf < 4; ++hf) o[hf][r] *= fr[r];
    }
    // stage P (bf16) into wave-private LDS, D-layout -> row-major [16][72]
#pragma unroll
    for (int cf = 0; cf < 4; ++cf)
#pragma unroll
      for (int r = 0; r < 4; ++r)
        Pl[wv][lg * 4 + r][cf * 16 + lrow] = f2bf(S[cf][r]);
    // PV: O += P @ V
#pragma unroll
    for (int s = 0; s < 2; ++s) {
      bf16x8 pa = *(const bf16x8*)((const char*)&Pl[wv][lrow][0] + s * 64 + lg * 16);
#pragma unroll
      for (int hf = 0; hf < 4; ++hf) {
        bf16x8 vf = *(const bf16x8*)(vb + (size_t)(hf * 16 + lrow) * TB + kv0 + s * 32 + lg * 8);
        o[hf] = __builtin_amdgcn_mfma_f32_16x16x32_bf16(pa, vf, o[hf], 0, 0, 0);
      }
    }
  }

#pragma unroll
  for (int hf = 0; hf < 4; ++hf)
#pragma unroll
    for (int r = 0; r < 4; ++r) {
      int rw = q0w + lg * 4 + r;
      out[((size_t)b * TB + rw) * 64 + hf * 16 + lrow] = o[hf][r] / ls[r];
    }
}

extern "C" void kernel_launch(void* const* d_in, const int* in_sizes, int n_in,
                              void* d_out, int out_size, void* d_ws, size_t ws_size,
                              hipStream_t stream) {
  const float* x  = (const float*)d_in[0];
  const float* Wq = (const float*)d_in[1];
  const float* Wk = (const float*)d_in[2];
  const float* Wv = (const float*)d_in[3];
  // workspace: Wt [192*768] | q [8192*64] | k [8192*64] | vT [4*64*2048]  (bf16)
  unsigned short* Wt = (unsigned short*)d_ws;
  unsigned short* qb = Wt + 192 * CB;
  unsigned short* kb = qb + (size_t)NB * TB * 64;
  unsigned short* vT = kb + (size_t)NB * TB * 64;
  float* out = (float*)d_out;

  hipLaunchKernelGGL(cvt_w_kernel, dim3((192 * CB + 255) / 256), dim3(256), 0, stream,
                     Wq, Wk, Wv, Wt);
  hipLaunchKernelGGL(proj_kernel, dim3((NB * TB) / 64), dim3(256), 0, stream,
                     x, Wt, qb, kb, vT);
  hipLaunchKernelGGL(attn_kernel, dim3(TB / 32, NB), dim3(128), 0, stream,
                     qb, kb, vT, out);
}

// Round 2
// 75.708 us; speedup vs baseline: 1.2623x; 1.2623x over previous
//
#include <hip/hip_runtime.h>
#include <math.h>

// B=4, T=2048, C=768, H=64
#define TB 2048
#define CB 768
#define NB 4
#define NROWS (NB * TB) // 8192

typedef __attribute__((ext_vector_type(8))) short bf16x8;
typedef __attribute__((ext_vector_type(4))) float f32x4;

__device__ inline unsigned short f2bf(float f) {
  union { float f; unsigned u; } v; v.f = f;
  unsigned r = v.u + 0x7FFFu + ((v.u >> 16) & 1u);
  return (unsigned short)(r >> 16);
}

// ---------------- kernel 0: weights fp32 [C][64] x3 -> Wt bf16 [192][768] ----
__global__ void cvt_w_kernel(const float* __restrict__ Wq, const float* __restrict__ Wk,
                             const float* __restrict__ Wv, unsigned short* __restrict__ Wt) {
  int id = blockIdx.x * 256 + threadIdx.x;
  if (id >= 192 * CB) return;
  int j = id / CB, c = id - j * CB;
  const float* W = (j < 64) ? Wq : (j < 128) ? Wk : Wv;
  Wt[id] = f2bf(W[c * 64 + (j & 63)]);
}

// ---------------- kernel 1: QKV projection GEMM, K-split ---------------------
// x [8192][768] fp32 @ Wt^T -> part fp32 [SK][8192][192]
__launch_bounds__(256)
__global__ void proj_kernel(const float* __restrict__ x, const unsigned short* __restrict__ Wt,
                            float* __restrict__ part, int ksteps) {
  __shared__ __align__(16) unsigned short xs[64 * 64]; // 64 rows x 64 k, bf16, XOR-swizzled
  const int tid = threadIdx.x;
  const int wv = tid >> 6;
  const int l = tid & 63;
  const int lrow = l & 15, lg = l >> 4;
  const int m0 = blockIdx.x * 64;
  const int ks = blockIdx.y;
  const int kbase = ks * ksteps * 64;
  const int srow = tid >> 2;
  const int sq = tid & 3;
  const float* xp = x + (size_t)(m0 + srow) * CB + sq * 16;

  f32x4 acc[4][3];
#pragma unroll
  for (int a = 0; a < 4; ++a)
#pragma unroll
    for (int n = 0; n < 3; ++n) acc[a][n] = (f32x4){0.f, 0.f, 0.f, 0.f};

  for (int kk = 0; kk < ksteps; ++kk) {
    int k0 = kbase + kk * 64;
    bf16x8 c0, c1;
#pragma unroll
    for (int i = 0; i < 2; ++i) {
      float4 f = *(const float4*)(xp + k0 + 4 * i);
      c0[4 * i + 0] = (short)f2bf(f.x); c0[4 * i + 1] = (short)f2bf(f.y);
      c0[4 * i + 2] = (short)f2bf(f.z); c0[4 * i + 3] = (short)f2bf(f.w);
    }
#pragma unroll
    for (int i = 0; i < 2; ++i) {
      float4 f = *(const float4*)(xp + k0 + 8 + 4 * i);
      c1[4 * i + 0] = (short)f2bf(f.x); c1[4 * i + 1] = (short)f2bf(f.y);
      c1[4 * i + 2] = (short)f2bf(f.z); c1[4 * i + 3] = (short)f2bf(f.w);
    }
    {
      char* base = (char*)xs + srow * 128;
      int swz = (srow & 7) << 4;
      *(bf16x8*)(base + ((sq * 32 + 0) ^ swz)) = c0;
      *(bf16x8*)(base + ((sq * 32 + 16) ^ swz)) = c1;
    }
    __syncthreads();

#pragma unroll
    for (int s = 0; s < 2; ++s) {
      bf16x8 af[4], bfr[3];
#pragma unroll
      for (int mf = 0; mf < 4; ++mf) {
        int r = mf * 16 + lrow;
        af[mf] = *(const bf16x8*)((const char*)xs + r * 128 +
                                  ((s * 64 + lg * 16) ^ ((r & 7) << 4)));
      }
#pragma unroll
      for (int nf = 0; nf < 3; ++nf) {
        int col = wv * 48 + nf * 16 + lrow;
        bfr[nf] = *(const bf16x8*)(Wt + (size_t)col * CB + k0 + s * 32 + lg * 8);
      }
#pragma unroll
      for (int mf = 0; mf < 4; ++mf)
#pragma unroll
        for (int nf = 0; nf < 3; ++nf)
          acc[mf][nf] = __builtin_amdgcn_mfma_f32_16x16x32_bf16(af[mf], bfr[nf], acc[mf][nf], 0, 0, 0);
    }
    __syncthreads();
  }

  // epilogue: partial fp32 write. D row = 16*mf + 4*lg + r, col = 48*wv + 16*nf + lrow
  float* pb = part + (size_t)ks * NROWS * 192;
#pragma unroll
  for (int mf = 0; mf < 4; ++mf)
#pragma unroll
    for (int nf = 0; nf < 3; ++nf)
#pragma unroll
      for (int r = 0; r < 4; ++r) {
        int grow = m0 + mf * 16 + lg * 4 + r;
        int j = wv * 48 + nf * 16 + lrow;
        pb[(size_t)grow * 192 + j] = acc[mf][nf][r];
      }
}

// ---------------- kernel 1b: reduce K-splits -> q,k bf16 ---------------------
__global__ void reduce_qk_kernel(const float* __restrict__ part, unsigned short* __restrict__ q,
                                 unsigned short* __restrict__ k, int SK) {
  int id = blockIdx.x * 256 + threadIdx.x;
  if (id >= NROWS * 128) return;
  int row = id >> 7, col = id & 127;
  float s = 0.f;
  for (int ks = 0; ks < SK; ++ks) s += part[((size_t)ks * NROWS + row) * 192 + col];
  unsigned short v = f2bf(s);
  if (col < 64) q[(size_t)row * 64 + col] = v;
  else          k[(size_t)row * 64 + (col - 64)] = v;
}

// ---------------- kernel 1c: reduce K-splits + transpose -> vT bf16 ----------
__global__ void reduce_v_kernel(const float* __restrict__ part, unsigned short* __restrict__ vT,
                                int SK) {
  __shared__ float tr[64][17];
  const int t0 = blockIdx.x * 16;
  const int b = blockIdx.y;
  const int c = threadIdx.x & 63, trow = threadIdx.x >> 6;
#pragma unroll
  for (int p = 0; p < 4; ++p) {
    int tl = p * 4 + trow;
    int row = b * TB + t0 + tl;
    float s = 0.f;
    for (int ks = 0; ks < SK; ++ks) s += part[((size_t)ks * NROWS + row) * 192 + 128 + c];
    tr[c][tl] = s;
  }
  __syncthreads();
  const int tl = threadIdx.x & 15, hb = threadIdx.x >> 4;
#pragma unroll
  for (int p = 0; p < 4; ++p) {
    int h = hb + p * 16;
    vT[((size_t)(b * 64 + h)) * TB + t0 + tl] = f2bf(tr[h][tl]);
  }
}

// ---------------- kernel 2: causal flash attention, KV-split -----------------
// grid (T/32, NS, B), block 128 (2 waves x 16 Q-rows)
__launch_bounds__(128)
__global__ void attn_kernel(const unsigned short* __restrict__ q,
                            const unsigned short* __restrict__ k,
                            const unsigned short* __restrict__ vT,
                            float* __restrict__ PO, float* __restrict__ ML, int NS) {
  __shared__ __align__(16) unsigned short Pl[2][16][72];
  const int tid = threadIdx.x;
  const int wv = tid >> 6, l = tid & 63;
  const int lrow = l & 15, lg = l >> 4;
  const int qt = blockIdx.x, sp = blockIdx.y, b = blockIdx.z;
  const int q0 = qt * 32;
  const int q0w = q0 + wv * 16;
  const int nb = (q0 + 32 + 63) >> 6;
  const int b0 = (sp * nb) / NS, b1 = ((sp + 1) * nb) / NS;
  const unsigned short* qb = q + (size_t)b * TB * 64;
  const unsigned short* kb = k + (size_t)b * TB * 64;
  const unsigned short* vb = vT + (size_t)b * 64 * TB;

  bf16x8 qf[2];
#pragma unroll
  for (int s = 0; s < 2; ++s)
    qf[s] = *(const bf16x8*)(qb + (size_t)(q0w + lrow) * 64 + s * 32 + lg * 8);

  float m[4], ls[4];
  f32x4 o[4];
#pragma unroll
  for (int r = 0; r < 4; ++r) { m[r] = -INFINITY; ls[r] = 0.f; }
#pragma unroll
  for (int hf = 0; hf < 4; ++hf) o[hf] = (f32x4){0.f, 0.f, 0.f, 0.f};

  const float scale = 0.03608439182435161f; // 768^-0.5

  for (int blk = b0; blk < b1; ++blk) {
    const int kv0 = blk * 64;
    f32x4 S[4];
#pragma unroll
    for (int cf = 0; cf < 4; ++cf) S[cf] = (f32x4){0.f, 0.f, 0.f, 0.f};
#pragma unroll
    for (int cf = 0; cf < 4; ++cf) {
      const unsigned short* kp = kb + (size_t)(kv0 + cf * 16 + lrow) * 64 + lg * 8;
#pragma unroll
      for (int s = 0; s < 2; ++s) {
        bf16x8 kf = *(const bf16x8*)(kp + s * 32);
        S[cf] = __builtin_amdgcn_mfma_f32_16x16x32_bf16(qf[s], kf, S[cf], 0, 0, 0);
      }
    }
    const bool msk = (kv0 + 63 > q0w);
#pragma unroll
    for (int cf = 0; cf < 4; ++cf)
#pragma unroll
      for (int r = 0; r < 4; ++r) {
        float vv = S[cf][r] * scale;
        if (msk) {
          int rw = q0w + lg * 4 + r, cl = kv0 + cf * 16 + lrow;
          if (cl > rw) vv = -INFINITY;
        }
        S[cf][r] = vv;
      }
    float fr[4], rs[4];
#pragma unroll
    for (int r = 0; r < 4; ++r) {
      float v = fmaxf(fmaxf(S[0][r], S[1][r]), fmaxf(S[2][r], S[3][r]));
      v = fmaxf(v, __shfl_xor(v, 1, 16));
      v = fmaxf(v, __shfl_xor(v, 2, 16));
      v = fmaxf(v, __shfl_xor(v, 4, 16));
      v = fmaxf(v, __shfl_xor(v, 8, 16));
      float mn = fmaxf(m[r], v);
      fr[r] = __expf(m[r] - mn);
      m[r] = mn;
      rs[r] = 0.f;
    }
#pragma unroll
    for (int cf = 0; cf < 4; ++cf)
#pragma unroll
      for (int r = 0; r < 4; ++r) {
        float p = __expf(S[cf][r] - m[r]);
        S[cf][r] = p;
        rs[r] += p;
      }
#pragma unroll
    for (int r = 0; r < 4; ++r) {
      float v = rs[r];
      v += __shfl_xor(v, 1, 16);
      v += __shfl_xor(v, 2, 16);
      v += __shfl_xor(v, 4, 16);
      v += __shfl_xor(v, 8, 16);
      ls[r] = ls[r] * fr[r] + v;
#pragma unroll
      for (int hf = 0; hf < 4; ++hf) o[hf][r] *= fr[r];
    }
#pragma unroll
    for (int cf = 0; cf < 4; ++cf)
#pragma unroll
      for (int r = 0; r < 4; ++r)
        Pl[wv][lg * 4 + r][cf * 16 + lrow] = f2bf(S[cf][r]);
#pragma unroll
    for (int s = 0; s < 2; ++s) {
      bf16x8 pa = *(const bf16x8*)((const char*)&Pl[wv][lrow][0] + s * 64 + lg * 16);
#pragma unroll
      for (int hf = 0; hf < 4; ++hf) {
        bf16x8 vf = *(const bf16x8*)(vb + (size_t)(hf * 16 + lrow) * TB + kv0 + s * 32 + lg * 8);
        o[hf] = __builtin_amdgcn_mfma_f32_16x16x32_bf16(pa, vf, o[hf], 0, 0, 0);
      }
    }
  }

  // write partials (unnormalized O, plus m,l per row)
#pragma unroll
  for (int hf = 0; hf < 4; ++hf)
#pragma unroll
    for (int r = 0; r < 4; ++r) {
      int rw = q0w + lg * 4 + r;
      PO[((size_t)(b * TB + rw) * NS + sp) * 64 + hf * 16 + lrow] = o[hf][r];
    }
  if (lrow == 0) {
#pragma unroll
    for (int r = 0; r < 4; ++r) {
      int rw = q0w + lg * 4 + r;
      ML[((size_t)(b * TB + rw) * NS + sp) * 2 + 0] = m[r];
      ML[((size_t)(b * TB + rw) * NS + sp) * 2 + 1] = ls[r];
    }
  }
}

// ---------------- kernel 2b: combine KV-splits -------------------------------
__global__ void attn_reduce_kernel(const float* __restrict__ PO, const float* __restrict__ ML,
                                   float* __restrict__ out, int NS) {
  int id = blockIdx.x * 256 + threadIdx.x;
  if (id >= NB * TB * 64) return;
  int h = id & 63;
  int row = id >> 6; // b*TB + t
  float M = -INFINITY;
  for (int s = 0; s < NS; ++s) M = fmaxf(M, ML[((size_t)row * NS + s) * 2]);
  float L = 0.f, o = 0.f;
  for (int s = 0; s < NS; ++s) {
    float w = __expf(ML[((size_t)row * NS + s) * 2] - M);
    L += ML[((size_t)row * NS + s) * 2 + 1] * w;
    o += PO[((size_t)row * NS + s) * 64 + h] * w;
  }
  out[(size_t)row * 64 + h] = o / L;
}

extern "C" void kernel_launch(void* const* d_in, const int* in_sizes, int n_in,
                              void* d_out, int out_size, void* d_ws, size_t ws_size,
                              hipStream_t stream) {
  const float* x  = (const float*)d_in[0];
  const float* Wq = (const float*)d_in[1];
  const float* Wk = (const float*)d_in[2];
  const float* Wv = (const float*)d_in[3];
  float* out = (float*)d_out;

  // ws layout: Wt | q | k | vT (bf16) | scratch (proj partials, later attn partials)
  unsigned short* Wt = (unsigned short*)d_ws;
  unsigned short* qb = Wt + 192 * CB;
  unsigned short* kb = qb + (size_t)NROWS * 64;
  unsigned short* vT = kb + (size_t)NROWS * 64;
  char* scratch = (char*)(vT + (size_t)NROWS * 64);
  size_t used_base = (size_t)(scratch - (char*)d_ws);

  auto scratch_need = [](int SK, int NS) -> size_t {
    size_t p = (size_t)SK * NROWS * 192 * 4;
    size_t a = (size_t)NS * NB * TB * 64 * 4 + (size_t)NS * NB * TB * 2 * 4;
    return p > a ? p : a;
  };
  int SK = 4, NS = 8;
  if (used_base + scratch_need(SK, NS) > ws_size) { SK = 2; NS = 4; }
  if (used_base + scratch_need(SK, NS) > ws_size) { SK = 1; NS = 2; }
  if (used_base + scratch_need(SK, NS) > ws_size) { SK = 1; NS = 1; }

  float* part = (float*)scratch;
  float* PO = (float*)scratch;
  float* ML = PO + (size_t)NS * NB * TB * 64;

  hipLaunchKernelGGL(cvt_w_kernel, dim3((192 * CB + 255) / 256), dim3(256), 0, stream,
                     Wq, Wk, Wv, Wt);
  hipLaunchKernelGGL(proj_kernel, dim3(NROWS / 64, SK), dim3(256), 0, stream,
                     x, Wt, part, CB / (64 * SK));
  hipLaunchKernelGGL(reduce_qk_kernel, dim3((NROWS * 128) / 256), dim3(256), 0, stream,
                     part, qb, kb, SK);
  hipLaunchKernelGGL(reduce_v_kernel, dim3(TB / 16, NB), dim3(256), 0, stream,
                     part, vT, SK);
  hipLaunchKernelGGL(attn_kernel, dim3(TB / 32, NS, NB), dim3(128), 0, stream,
                     qb, kb, vT, PO, ML, NS);
  hipLaunchKernelGGL(attn_reduce_kernel, dim3((NB * TB * 64) / 256), dim3(256), 0, stream,
                     PO, ML, out, NS);
}